// Round 9
// baseline (571.823 us; speedup 1.0000x reference)
//
#include <hip/hip_runtime.h>

// GCN forward: 2× (GCNConv) + mean-pool + linear head. 6-dispatch pipeline:
//   k_partw: 782-range edge split (packed int) + W1 bf16 pack + w2l
//   k_build: per-range CSR build + t8 = (x@W1)*dinv bf16 MFMA (slice-major)
//   k_agg1:  XCD-local slice gather -> q8 partial dots
//   k_qred:  q = sum_slices q8
//   k_agg2:  16-lane/node gather of q (p scalars out)
//   k_pool:  sorted-batch segment mean + head
//
// R6: collapsed layer-2 scalar q table: 785->636.  R8: bf16 MFMA mm.
// R7: shared-line scatter REGRESSED (cross-XCD lines never merge).
// R10: XCD-local scatter: 617->583.  R11: bf16 t quad-rows: ->560.
// R12: atomic-free pool: 560->442.  R13: range-owned CSR build: 442->344.
// R14/R15: agg1 batching/persistent-pipeline: NEUTRAL at 67us.
// R16: 11->5 dispatches: only -3.5us -> launch-gap theory dead; hidden time
//     is inside sub-top-5 kernels (build/partw/agg2 each just under 68).
// R17: agg1's 188MB FETCH = 8 XCDs x 25.6MB t = L2 CAPACITY problem.
//     q separable across features -> slice t into 8x 3.2MB (slice-major,
//     < 4MB L2/XCD); slice s handled only by blocks blockIdx&7==s (XCD
//     round-robin) -> gathers become XCD-L2-resident. q8[s][node] partials
//     (single-XCD writer per region), k_qred sums. k_build Phase A:
//     wave-cooperative coalesced segment reads (was 5-deep serial 4B
//     chains), SCAP 24->16KB -> 3 blocks/CU.

typedef __attribute__((ext_vector_type(8))) short short8;
typedef __attribute__((ext_vector_type(4))) float f32x4;

#define CHUNK 4096   // edges per k_partw block (16 KB LDS stage, packed)
#define RW    128    // nodes per range (r = d >> 7)
#define SCAP  4096   // build LDS edge-stage capacity (2x expected 2048)
#define JCAP  512    // build per-chunk base table capacity
#define WCAP  6144   // static srt window per range (3x Poisson(2048) mean)

__device__ __forceinline__ unsigned short bf16r(float f) {
    unsigned u = __float_as_uint(f);
    u += 0x7FFFu + ((u >> 16) & 1u);
    return (unsigned short)(u >> 16);
}

__device__ __forceinline__ float bff(unsigned short u) {
    return __uint_as_float((unsigned)u << 16);
}

// Fused: blocks [0,nchunks) = edge partition; blocks [nchunks,nchunks+64) =
// W1 bf16 pack; block nchunks+64 = w2l.
__global__ __launch_bounds__(256) void k_partw(
    const int* __restrict__ src, const int* __restrict__ dst,
    int* __restrict__ part, int* __restrict__ off_t, int* __restrict__ cnt_t,
    const float* __restrict__ W1, unsigned short* __restrict__ w1p,
    const float* __restrict__ W2, const float* __restrict__ Wl,
    float* __restrict__ w2l, int E, int nchunks, int NR)
{
    int tid = threadIdx.x;
    if (blockIdx.x >= nchunks) {
        int b = blockIdx.x - nchunks;
        if (b == 64) {
            if (tid < 128) {
                float s = 0.0f;
                for (int j = 0; j < 128; ++j) s = fmaf(W2[tid * 128 + j], Wl[j], s);
                w2l[tid] = s;
            }
            return;
        }
        int idx = b * 256 + tid;   // < 16384
        int k = idx >> 7, n = idx & 127;
        w1p[((k >> 3) * 128 + n) * 8 + (k & 7)] = bf16r(W1[idx]);
        return;
    }

    __shared__ int stage[CHUNK];         // 16 KB packed edges
    __shared__ int lcnt[1024];           // histogram / scan ping
    __shared__ int lscan[1024];          // scan pong
    int j = blockIdx.x;
    int base = j * CHUNK;

#pragma unroll
    for (int k = 0; k < 4; ++k) lcnt[tid + k * 256] = 0;
    __syncthreads();

    int mye[16], myr[16];
#pragma unroll
    for (int k = 0; k < 16; ++k) {
        int e = base + tid + (k << 8);
        bool ok = e < E;
        int s = ok ? src[e] : 0;
        int d = ok ? dst[e] : 0;
        int r = -1;
        if (ok) {
            r = d >> 7;
            atomicAdd(&lcnt[r], 1);
        }
        mye[k] = (s << 7) | (d & 127);
        myr[k] = r;
    }
    __syncthreads();

    // inclusive Hillis-Steele scan over 1024 (ping-pong)
    int* pa = lcnt;
    int* pb = lscan;
    for (int off = 1; off < 1024; off <<= 1) {
#pragma unroll
        for (int k = 0; k < 4; ++k) {
            int idx = tid + k * 256;
            int v = pa[idx];
            if (idx >= off) v += pa[idx - off];
            pb[idx] = v;
        }
        __syncthreads();
        int* tmp = pa; pa = pb; pb = tmp;
    }
    // pa = inclusive scan; pb free -> cursor array
    for (int i = tid; i < NR; i += 256) {
        int incl = pa[i];
        int excl = (i == 0) ? 0 : pa[i - 1];
        pb[i] = excl;
        off_t[(size_t)i * nchunks + j] = excl;
        cnt_t[(size_t)i * nchunks + j] = incl - excl;
    }
    __syncthreads();

#pragma unroll
    for (int k = 0; k < 16; ++k) {
        if (myr[k] >= 0) {
            int p = atomicAdd(&pb[myr[k]], 1);
            stage[p] = mye[k];
        }
    }
    __syncthreads();

    int valid = E - base; if (valid > CHUNK) valid = CHUNK;
    for (int i = tid; i < valid; i += 256)
        part[(size_t)base + i] = stage[i];
}

// Fused build: one block per range. Phase A: wave-cooperative coalesced
// staging of this range's packed edges + LDS histogram. Phase B: LDS scan ->
// rps/rpe/dinv/cursors (static window base r*WCAP). Phase C: scatter from
// LDS into private srt window. Phase D: t8 rows (slice-major) via bf16 MFMA.
__global__ __launch_bounds__(256) void k_build(
    const int* __restrict__ part, const int* __restrict__ off_t,
    const int* __restrict__ cnt_t, const float* __restrict__ x,
    const unsigned short* __restrict__ w1p, int* __restrict__ srt,
    int* __restrict__ rps, int* __restrict__ rpe, float* __restrict__ dinv,
    unsigned short* __restrict__ t8, int nchunks, int N, int NR)
{
    __shared__ int stage[SCAP];          // 16 KB
    __shared__ int jbase[JCAP];          // 2 KB
    __shared__ int hist[RW], lcur[RW], s1[RW], s2[RW];
    __shared__ float dins[RW];
    __shared__ int cursor;
    __shared__ unsigned short w1s[16384]; // 32 KB packed bf16 W1
    int r = blockIdx.x;
    int tid = threadIdx.x;
    int wave = tid >> 6, lane = tid & 63;
    int d0 = r << 7;
    int width = N - d0; if (width > RW) width = RW;

    {   // W1 -> LDS
        const uint4* s = (const uint4*)w1p;
        uint4* d = (uint4*)w1s;
#pragma unroll
        for (int i = 0; i < 8; ++i) d[tid + i * 256] = s[tid + i * 256];
    }
    if (tid < RW) hist[tid] = 0;
    if (tid == 0) cursor = 0;
    __syncthreads();

    const int* orow = off_t + (size_t)r * nchunks;
    const int* crow = cnt_t + (size_t)r * nchunks;

    // Phase A: wave-cooperative stage + histogram (coalesced segment reads)
    for (int j = wave; j < nchunks; j += 4) {
        int c = crow[j];
        if (c == 0) { if (lane == 0 && j < JCAP) jbase[j] = 0; continue; }
        int b = 0;
        if (lane == 0) {
            b = atomicAdd(&cursor, c);
            if (j < JCAP) jbase[j] = b;
        }
        b = __shfl(b, 0);
        const int* pp = part + (size_t)j * CHUNK + orow[j];
        for (int e = lane; e < c; e += 64) {
            int ed = pp[e];
            int pos = b + e;
            if (pos < SCAP) stage[pos] = ed;
            atomicAdd(&hist[ed & 127], 1);
        }
    }
    __syncthreads();
    int total = cursor;

    // Phase B: exclusive scan of hist -> rps/rpe/dinv/cursors
    if (tid < RW) s1[tid] = hist[tid];
    __syncthreads();
    int* pa = s1; int* pb = s2;
    for (int off = 1; off < RW; off <<= 1) {
        if (tid < RW) {
            int v = pa[tid];
            if (tid >= off) v += pa[tid - off];
            pb[tid] = v;
        }
        __syncthreads();
        int* tmp = pa; pa = pb; pb = tmp;
    }
    int wbase = r * WCAP;
    if (tid < width) {
        int excl = (tid == 0) ? 0 : pa[tid - 1];
        int start = wbase + excl;
        int deg = hist[tid];
        rps[d0 + tid] = start;
        rpe[d0 + tid] = start + deg;
        lcur[tid] = start;
        float di = 1.0f / sqrtf((float)deg + 1.0f);
        dins[tid] = di;
        dinv[d0 + tid] = di;
    }
    __syncthreads();

    // Phase C: scatter from LDS stage into private window
    int lim = total < SCAP ? total : SCAP;
    for (int i = tid; i < lim; i += 256) {
        int ed = stage[i];
        int pos = atomicAdd(&lcur[ed & 127], 1);
        srt[pos] = ed >> 7;
    }
    // Overflow fallback (not expected at these sizes)
    if (total > SCAP || nchunks > JCAP) {
        for (int j = tid; j < nchunks; j += 256) {
            int c = crow[j];
            if (c == 0) continue;
            int e0 = 0;
            if (j < JCAP) {
                int b = jbase[j];
                e0 = SCAP - b;
                if (e0 < 0) e0 = 0;
                if (e0 >= c) continue;
            }
            const int* pp = part + (size_t)j * CHUNK + orow[j];
            for (int e = e0; e < c; ++e) {
                int ed = pp[e];
                int pos = atomicAdd(&lcur[ed & 127], 1);
                srt[pos] = ed >> 7;
            }
        }
    }

    // Phase D: t8 rows for this range = (x@W1)*dinv, bf16 MFMA, slice-major:
    // t8[cg][row][m], cg = 16-feature slice.
    int w = wave;
    int m = lane & 15, quad = lane >> 4;
    int r0 = d0 + w * 32;

    f32x4 acc[2][8];
#pragma unroll
    for (int rg = 0; rg < 2; ++rg)
#pragma unroll
        for (int cg = 0; cg < 8; ++cg) {
            f32x4 z = {0.0f, 0.0f, 0.0f, 0.0f};
            acc[rg][cg] = z;
        }

#pragma unroll
    for (int ks = 0; ks < 4; ++ks) {
        int k0 = ks * 32 + quad * 8;
        short8 a[2];
#pragma unroll
        for (int rg = 0; rg < 2; ++rg) {
            int rr = r0 + rg * 16 + m;
            if (rr > N - 1) rr = N - 1;
            const float* ap = x + (size_t)rr * 128 + k0;
            float4 v0 = *(const float4*)ap;
            float4 v1 = *(const float4*)(ap + 4);
            short8 av;
            av[0] = (short)bf16r(v0.x); av[1] = (short)bf16r(v0.y);
            av[2] = (short)bf16r(v0.z); av[3] = (short)bf16r(v0.w);
            av[4] = (short)bf16r(v1.x); av[5] = (short)bf16r(v1.y);
            av[6] = (short)bf16r(v1.z); av[7] = (short)bf16r(v1.w);
            a[rg] = av;
        }
        int kc = ks * 4 + quad;
#pragma unroll
        for (int cg = 0; cg < 8; ++cg) {
            const short8* bp = (const short8*)&w1s[((size_t)kc * 128 + cg * 16 + m) * 8];
            short8 b = *bp;
            acc[0][cg] = __builtin_amdgcn_mfma_f32_16x16x32_bf16(a[0], b, acc[0][cg], 0, 0, 0);
            acc[1][cg] = __builtin_amdgcn_mfma_f32_16x16x32_bf16(a[1], b, acc[1][cg], 0, 0, 0);
        }
    }

    // C/D layout: col = lane&15, row = quad*4 + reg
#pragma unroll
    for (int rg = 0; rg < 2; ++rg) {
        int rb = r0 + rg * 16 + quad * 4;
#pragma unroll
        for (int reg = 0; reg < 4; ++reg) {
            int row = rb + reg;
            if (row < N) {
                float s = dins[row - d0];
#pragma unroll
                for (int cg = 0; cg < 8; ++cg)
                    t8[((size_t)cg * (N + 1) + row) * 16 + m] =
                        bf16r(acc[rg][cg][reg] * s);
            }
        }
    }

    // zero pad row N of each slice (replaces memset dispatch)
    if (r == NR - 1 && tid < 16) {
        int sl = tid >> 1, half = tid & 1;
        uint4 z = {0u, 0u, 0u, 0u};
        *(uint4*)(t8 + ((size_t)sl * (N + 1) + N) * 16 + half * 8) = z;
    }
}

// R17 agg1: XCD-local slice gather. Slice sl = blockIdx&7 (round-robin ->
// one XCD owns one 3.2MB t8 slice, L2-resident). Wave per node per slice:
// 8 edges x 8 feature-lanes per load instr (idx shfl-broadcast, no LDS).
// Partial dot (relu separable across features) -> q8[sl][node].
__global__ __launch_bounds__(256) void k_agg1(
    const unsigned short* __restrict__ t8, const float* __restrict__ dinv,
    const int* __restrict__ rps, const int* __restrict__ rpe,
    const int* __restrict__ srt, const float* __restrict__ b1,
    const float* __restrict__ w2l, float* __restrict__ q8, int N, int gstride)
{
    int wave = threadIdx.x >> 6, lane = threadIdx.x & 63;
    int sl = blockIdx.x & 7;
    int wg = (blockIdx.x >> 3) * 4 + wave;     // wave id within slice group
    int f2 = lane & 7;                          // feature-pair index
    const unsigned short* tbase = t8 + (size_t)sl * (N + 1) * 16 + f2 * 2;
    float2 bb = *(const float2*)(b1 + sl * 16 + f2 * 2);
    float2 ww = *(const float2*)(w2l + sl * 16 + f2 * 2);
    float* qout = q8 + (size_t)sl * N;

    for (int node = wg; node < N; node += gstride) {
        int s0 = rps[node], s1 = rpe[node];
        int deg = s1 - s0;
        int vdeg = deg < 63 ? deg : 63;
        int idx = N;                            // pad -> zero row
        if (lane < vdeg) idx = srt[s0 + lane];
        else if (lane == vdeg) idx = node;      // self loop
        float a0 = 0.0f, a1 = 0.0f;
        int nb = (vdeg + 8) >> 3;               // ceil((vdeg+1)/8)
        for (int b = 0; b < nb; ++b) {
            int id = __shfl(idx, (b << 3) + (lane >> 3));
            unsigned u = *(const unsigned*)(tbase + (size_t)id * 16);
            a0 += bff((unsigned short)(u & 0xffff));
            a1 += bff((unsigned short)(u >> 16));
        }
        if (deg > 63) {                         // rare overflow path
            for (int e = s0 + 63; e < s1; ++e) {
                int id = srt[e];
                if (lane < 8) {
                    unsigned u = *(const unsigned*)(tbase + (size_t)id * 16);
                    a0 += bff((unsigned short)(u & 0xffff));
                    a1 += bff((unsigned short)(u >> 16));
                }
            }
        }
        // reduce over the 8 edge-slot groups (lane bits 3..5)
        a0 += __shfl_xor(a0, 8);  a1 += __shfl_xor(a1, 8);
        a0 += __shfl_xor(a0, 16); a1 += __shfl_xor(a1, 16);
        a0 += __shfl_xor(a0, 32); a1 += __shfl_xor(a1, 32);
        float di = dinv[node];
        float h0 = fmaxf(fmaf(a0, di, bb.x), 0.0f);
        float h1 = fmaxf(fmaf(a1, di, bb.y), 0.0f);
        float pr = h0 * ww.x + h1 * ww.y;
        // reduce over the 8 feature lanes (lane bits 0..2)
        pr += __shfl_xor(pr, 1);
        pr += __shfl_xor(pr, 2);
        pr += __shfl_xor(pr, 4);
        if (lane == 0) qout[node] = pr * di;
    }
}

// q[v] = sum over slices of q8[sl][v]  (8 coalesced streams).
__global__ __launch_bounds__(256) void k_qred(
    const float* __restrict__ q8, float* __restrict__ q, int N)
{
    int i = blockIdx.x * 256 + threadIdx.x;
    if (i < N) {
        float s = 0.0f;
#pragma unroll
        for (int sl = 0; sl < 8; ++sl) s += q8[(size_t)sl * N + i];
        q[i] = s;
    }
}

// agg2: 16 lanes per node, no atomics -> per-node p[] (coalesced store).
__global__ __launch_bounds__(256) void k_agg2(
    const float* __restrict__ q, const float* __restrict__ dinv,
    const int* __restrict__ rps, const int* __restrict__ rpe,
    const int* __restrict__ srt, float* __restrict__ p, int N)
{
    int tid = blockIdx.x * 256 + threadIdx.x;
    int node = tid >> 4;
    int l = tid & 15;
    if (node >= N) return;
    int s0 = rps[node], s1 = rpe[node];
    float a = 0.0f;
    for (int e = s0 + l; e < s1; e += 16) a += q[srt[e]];
#pragma unroll
    for (int off = 8; off > 0; off >>= 1) a += __shfl_xor(a, off);
    if (l == 0) p[node] = dinv[node] * (a + q[node]);
}

// pool: one wave per graph; batch sorted -> binary-search segment,
// coalesced sum. out[g] = mean + b2.Wl + bl.
__global__ __launch_bounds__(64) void k_pool(
    const float* __restrict__ p, const int* __restrict__ batch,
    const float* __restrict__ b2, const float* __restrict__ Wl,
    const float* __restrict__ bl, float* __restrict__ out, int N, int G)
{
    int g = blockIdx.x;
    int lane = threadIdx.x;
    __shared__ int sb[2];
    if (lane < 2) {
        int target = g + lane;
        int lo = 0, hi = N;
        while (lo < hi) {
            int mid = (lo + hi) >> 1;
            if (batch[mid] < target) lo = mid + 1; else hi = mid;
        }
        sb[lane] = lo;
    }
    __syncthreads();
    int s = sb[0], e = sb[1];
    float a = 0.0f;
    for (int i = s + lane; i < e; i += 64) a += p[i];
#pragma unroll
    for (int off = 32; off > 0; off >>= 1) a += __shfl_xor(a, off);
    if (lane == 0) {
        float c = 0.0f;
        for (int j = 0; j < 128; ++j) c = fmaf(b2[j], Wl[j], c);
        out[g] = a / fmaxf((float)(e - s), 1.0f) + c + bl[0];
    }
}

extern "C" void kernel_launch(void* const* d_in, const int* in_sizes, int n_in,
                              void* d_out, int out_size, void* d_ws, size_t ws_size,
                              hipStream_t stream)
{
    const float* x  = (const float*)d_in[0];
    const int*   ei = (const int*)d_in[1];
    // d_in[2] = edge_attr: unused by the reference
    const int*   batch = (const int*)d_in[3];
    const float* W1 = (const float*)d_in[4];
    const float* b1 = (const float*)d_in[5];
    const float* W2 = (const float*)d_in[6];
    const float* b2 = (const float*)d_in[7];
    const float* Wl = (const float*)d_in[8];
    const float* bl = (const float*)d_in[9];

    int N = in_sizes[0] / 128;
    int E = in_sizes[1] / 2;
    const int* src = ei;
    const int* dst = ei + E;

    char* ws = (char*)d_ws;
    size_t off = 0;
    auto alloc = [&](size_t bytes) -> void* {
        void* p = ws + off;
        off = (off + bytes + 255) & ~(size_t)255;
        return p;
    };
    int nchunks = (E + CHUNK - 1) / CHUNK;                   // 391
    int NR = (N + RW - 1) / RW;                              // 782 <= 1024
    unsigned short* t8 = (unsigned short*)alloc((size_t)8 * (N + 1) * 16 * 2); // slice-major bf16
    float* q8   = (float*)alloc((size_t)8 * N * 4);          // per-slice partial dots
    float* q    = (float*)alloc((size_t)N * 4);
    float* p    = (float*)alloc((size_t)N * 4);
    int*   srt  = (int*)alloc((size_t)NR * WCAP * 4);        // static windows (19.2MB)
    int*   part = (int*)alloc((size_t)nchunks * CHUNK * 4);  // packed (src<<7|d&127)
    int*   off_t= (int*)alloc((size_t)NR * nchunks * 4);
    int*   cnt_t= (int*)alloc((size_t)NR * nchunks * 4);
    float* dinv = (float*)alloc((size_t)N * 4);
    int*   rps  = (int*)alloc((size_t)N * 4);
    int*   rpe  = (int*)alloc((size_t)N * 4);
    float* w2l  = (float*)alloc(128 * 4);
    unsigned short* w1p = (unsigned short*)alloc(16384 * 2);
    (void)ws_size;

    k_partw<<<nchunks + 65, 256, 0, stream>>>(src, dst, part, off_t, cnt_t,
                                              W1, w1p, W2, Wl, w2l, E, nchunks, NR);
    k_build<<<NR, 256, 0, stream>>>(part, off_t, cnt_t, x, w1p, srt, rps, rpe,
                                    dinv, t8, nchunks, N, NR);
    int a1b = 2048;                      // 256 blocks per slice group
    k_agg1<<<a1b, 256, 0, stream>>>(t8, dinv, rps, rpe, srt, b1, w2l, q8, N,
                                    (a1b / 8) * 4);
    k_qred<<<(N + 255) / 256, 256, 0, stream>>>(q8, q, N);
    k_agg2<<<((size_t)N * 16 + 255) / 256, 256, 0, stream>>>(q, dinv, rps, rpe, srt, p, N);
    k_pool<<<512, 64, 0, stream>>>(p, batch, b2, Wl, bl, (float*)d_out, N, 512);
}

// Round 10
// 443.257 us; speedup vs baseline: 1.2900x; 1.2900x over previous
//
#include <hip/hip_runtime.h>

// GCN forward: 2× (GCNConv) + mean-pool + linear head. 6-dispatch pipeline:
//   k_partw: 782-range edge split (packed int) + W1 bf16 pack + w2l
//   k_build: per-range CSR build + t8 = (x@W1)*dinv bf16 MFMA (slice-major)
//   k_agg1:  XCD-local slice gather -> q8 partial dots
//   k_qred:  q = sum_slices q8
//   k_agg2:  16-lane/node gather of q (p scalars out)
//   k_pool:  sorted-batch segment mean + head
//
// R6: collapsed layer-2 scalar q table: 785->636.  R8: bf16 MFMA mm.
// R7: shared-line scatter REGRESSED (cross-XCD lines never merge).
// R10: XCD-local scatter: 617->583.  R11: bf16 t quad-rows: ->560.
// R12: atomic-free pool: 560->442.  R13: range-owned CSR build: 442->344.
// R14/R15: agg1 batching/persistent-pipeline: NEUTRAL at 67us (FETCH pinned
//     at 188MB = 8 XCD x 25.6MB t = L2 capacity, rate 2.9 TB/s).
// R16: 11->5 dispatches: only -3.5us -> launch gaps are NOT the hidden time;
//     kernels themselves sum to ~330 (build/agg2/partw each just under 68).
// R17: REGRESSED 332->572, cleanly attributed: k_build 195us (VALUBusy 9.9%,
//     occ 16.6%) from wave-cooperative Phase A -- avg segment is ~5 edges,
//     so 4 serial per-wave chains replaced 256 per-thread chains (MLP lost
//     ~60x). Slice-major t8 + XCD agg1 left UNJUDGED (masked by build).
// R18: revert Phase A to per-thread (SCAP 6144, R16 config), KEEP slice t8 +
//     XCD-local agg1 + qred to judge them in isolation.

typedef __attribute__((ext_vector_type(8))) short short8;
typedef __attribute__((ext_vector_type(4))) float f32x4;

#define CHUNK 4096   // edges per k_partw block (16 KB LDS stage, packed)
#define RW    128    // nodes per range (r = d >> 7)
#define SCAP  6144   // build LDS edge-stage capacity (3x expected 2048)
#define JCAP  512    // build per-chunk base table capacity
#define WCAP  6144   // static srt window per range (3x Poisson(2048) mean)

__device__ __forceinline__ unsigned short bf16r(float f) {
    unsigned u = __float_as_uint(f);
    u += 0x7FFFu + ((u >> 16) & 1u);
    return (unsigned short)(u >> 16);
}

__device__ __forceinline__ float bff(unsigned short u) {
    return __uint_as_float((unsigned)u << 16);
}

// Fused: blocks [0,nchunks) = edge partition; blocks [nchunks,nchunks+64) =
// W1 bf16 pack; block nchunks+64 = w2l.
__global__ __launch_bounds__(256) void k_partw(
    const int* __restrict__ src, const int* __restrict__ dst,
    int* __restrict__ part, int* __restrict__ off_t, int* __restrict__ cnt_t,
    const float* __restrict__ W1, unsigned short* __restrict__ w1p,
    const float* __restrict__ W2, const float* __restrict__ Wl,
    float* __restrict__ w2l, int E, int nchunks, int NR)
{
    int tid = threadIdx.x;
    if (blockIdx.x >= nchunks) {
        int b = blockIdx.x - nchunks;
        if (b == 64) {
            if (tid < 128) {
                float s = 0.0f;
                for (int j = 0; j < 128; ++j) s = fmaf(W2[tid * 128 + j], Wl[j], s);
                w2l[tid] = s;
            }
            return;
        }
        int idx = b * 256 + tid;   // < 16384
        int k = idx >> 7, n = idx & 127;
        w1p[((k >> 3) * 128 + n) * 8 + (k & 7)] = bf16r(W1[idx]);
        return;
    }

    __shared__ int stage[CHUNK];         // 16 KB packed edges
    __shared__ int lcnt[1024];           // histogram / scan ping
    __shared__ int lscan[1024];          // scan pong
    int j = blockIdx.x;
    int base = j * CHUNK;

#pragma unroll
    for (int k = 0; k < 4; ++k) lcnt[tid + k * 256] = 0;
    __syncthreads();

    int mye[16], myr[16];
#pragma unroll
    for (int k = 0; k < 16; ++k) {
        int e = base + tid + (k << 8);
        bool ok = e < E;
        int s = ok ? src[e] : 0;
        int d = ok ? dst[e] : 0;
        int r = -1;
        if (ok) {
            r = d >> 7;
            atomicAdd(&lcnt[r], 1);
        }
        mye[k] = (s << 7) | (d & 127);
        myr[k] = r;
    }
    __syncthreads();

    // inclusive Hillis-Steele scan over 1024 (ping-pong)
    int* pa = lcnt;
    int* pb = lscan;
    for (int off = 1; off < 1024; off <<= 1) {
#pragma unroll
        for (int k = 0; k < 4; ++k) {
            int idx = tid + k * 256;
            int v = pa[idx];
            if (idx >= off) v += pa[idx - off];
            pb[idx] = v;
        }
        __syncthreads();
        int* tmp = pa; pa = pb; pb = tmp;
    }
    // pa = inclusive scan; pb free -> cursor array
    for (int i = tid; i < NR; i += 256) {
        int incl = pa[i];
        int excl = (i == 0) ? 0 : pa[i - 1];
        pb[i] = excl;
        off_t[(size_t)i * nchunks + j] = excl;
        cnt_t[(size_t)i * nchunks + j] = incl - excl;
    }
    __syncthreads();

#pragma unroll
    for (int k = 0; k < 16; ++k) {
        if (myr[k] >= 0) {
            int p = atomicAdd(&pb[myr[k]], 1);
            stage[p] = mye[k];
        }
    }
    __syncthreads();

    int valid = E - base; if (valid > CHUNK) valid = CHUNK;
    for (int i = tid; i < valid; i += 256)
        part[(size_t)base + i] = stage[i];
}

// Fused build: one block per range. Phase A (per-thread chunk walks, 256
// independent chains -- R17's wave-coop version REGRESSED): stage packed
// edges in LDS + histogram. Phase B: LDS scan -> rps/rpe/dinv/cursors.
// Phase C: LDS-cursor scatter into private srt window. Phase D: slice-major
// t8 rows via bf16 MFMA (W1 in LDS).
__global__ __launch_bounds__(256) void k_build(
    const int* __restrict__ part, const int* __restrict__ off_t,
    const int* __restrict__ cnt_t, const float* __restrict__ x,
    const unsigned short* __restrict__ w1p, int* __restrict__ srt,
    int* __restrict__ rps, int* __restrict__ rpe, float* __restrict__ dinv,
    unsigned short* __restrict__ t8, int nchunks, int N, int NR)
{
    __shared__ int stage[SCAP];          // 24 KB
    __shared__ int jbase[JCAP];          // 2 KB
    __shared__ int hist[RW], lcur[RW], s1[RW], s2[RW];
    __shared__ float dins[RW];
    __shared__ int cursor;
    __shared__ unsigned short w1s[16384]; // 32 KB packed bf16 W1
    int r = blockIdx.x;
    int tid = threadIdx.x;
    int d0 = r << 7;
    int width = N - d0; if (width > RW) width = RW;

    {   // W1 -> LDS
        const uint4* s = (const uint4*)w1p;
        uint4* d = (uint4*)w1s;
#pragma unroll
        for (int i = 0; i < 8; ++i) d[tid + i * 256] = s[tid + i * 256];
    }
    if (tid < RW) hist[tid] = 0;
    if (tid == 0) cursor = 0;
    __syncthreads();

    const int* orow = off_t + (size_t)r * nchunks;
    const int* crow = cnt_t + (size_t)r * nchunks;

    // Phase A: per-thread stage + histogram (256 independent chains)
    for (int j = tid; j < nchunks; j += 256) {
        int c = crow[j];
        if (c == 0) { if (j < JCAP) jbase[j] = 0; continue; }
        int b = (j < JCAP) ? atomicAdd(&cursor, c) : SCAP;
        if (j < JCAP) jbase[j] = b;
        const int* pp = part + (size_t)j * CHUNK + orow[j];
        for (int e = 0; e < c; ++e) {
            int ed = pp[e];
            int pos = b + e;
            if (pos < SCAP) stage[pos] = ed;
            atomicAdd(&hist[ed & 127], 1);
        }
    }
    __syncthreads();
    int total = cursor;

    // Phase B: exclusive scan of hist -> rps/rpe/dinv/cursors
    if (tid < RW) s1[tid] = hist[tid];
    __syncthreads();
    int* pa = s1; int* pb = s2;
    for (int off = 1; off < RW; off <<= 1) {
        if (tid < RW) {
            int v = pa[tid];
            if (tid >= off) v += pa[tid - off];
            pb[tid] = v;
        }
        __syncthreads();
        int* tmp = pa; pa = pb; pb = tmp;
    }
    int wbase = r * WCAP;
    if (tid < width) {
        int excl = (tid == 0) ? 0 : pa[tid - 1];
        int start = wbase + excl;
        int deg = hist[tid];
        rps[d0 + tid] = start;
        rpe[d0 + tid] = start + deg;
        lcur[tid] = start;
        float di = 1.0f / sqrtf((float)deg + 1.0f);
        dins[tid] = di;
        dinv[d0 + tid] = di;
    }
    __syncthreads();

    // Phase C: scatter from LDS stage into private window
    int lim = total < SCAP ? total : SCAP;
    for (int i = tid; i < lim; i += 256) {
        int ed = stage[i];
        int pos = atomicAdd(&lcur[ed & 127], 1);
        srt[pos] = ed >> 7;
    }
    // Overflow fallback (not expected at these sizes)
    if (total > SCAP || nchunks > JCAP) {
        for (int j = tid; j < nchunks; j += 256) {
            int c = crow[j];
            if (c == 0) continue;
            int e0 = 0;
            if (j < JCAP) {
                int b = jbase[j];
                e0 = SCAP - b;
                if (e0 < 0) e0 = 0;
                if (e0 >= c) continue;
            }
            const int* pp = part + (size_t)j * CHUNK + orow[j];
            for (int e = e0; e < c; ++e) {
                int ed = pp[e];
                int pos = atomicAdd(&lcur[ed & 127], 1);
                srt[pos] = ed >> 7;
            }
        }
    }

    // Phase D: slice-major t8 rows = (x@W1)*dinv, bf16 MFMA:
    // t8[cg][row][m], cg = 16-feature slice.
    int w = tid >> 6, lane = tid & 63;
    int m = lane & 15, quad = lane >> 4;
    int r0 = d0 + w * 32;

    f32x4 acc[2][8];
#pragma unroll
    for (int rg = 0; rg < 2; ++rg)
#pragma unroll
        for (int cg = 0; cg < 8; ++cg) {
            f32x4 z = {0.0f, 0.0f, 0.0f, 0.0f};
            acc[rg][cg] = z;
        }

#pragma unroll
    for (int ks = 0; ks < 4; ++ks) {
        int k0 = ks * 32 + quad * 8;
        short8 a[2];
#pragma unroll
        for (int rg = 0; rg < 2; ++rg) {
            int rr = r0 + rg * 16 + m;
            if (rr > N - 1) rr = N - 1;
            const float* ap = x + (size_t)rr * 128 + k0;
            float4 v0 = *(const float4*)ap;
            float4 v1 = *(const float4*)(ap + 4);
            short8 av;
            av[0] = (short)bf16r(v0.x); av[1] = (short)bf16r(v0.y);
            av[2] = (short)bf16r(v0.z); av[3] = (short)bf16r(v0.w);
            av[4] = (short)bf16r(v1.x); av[5] = (short)bf16r(v1.y);
            av[6] = (short)bf16r(v1.z); av[7] = (short)bf16r(v1.w);
            a[rg] = av;
        }
        int kc = ks * 4 + quad;
#pragma unroll
        for (int cg = 0; cg < 8; ++cg) {
            const short8* bp = (const short8*)&w1s[((size_t)kc * 128 + cg * 16 + m) * 8];
            short8 b = *bp;
            acc[0][cg] = __builtin_amdgcn_mfma_f32_16x16x32_bf16(a[0], b, acc[0][cg], 0, 0, 0);
            acc[1][cg] = __builtin_amdgcn_mfma_f32_16x16x32_bf16(a[1], b, acc[1][cg], 0, 0, 0);
        }
    }

    // C/D layout: col = lane&15, row = quad*4 + reg
#pragma unroll
    for (int rg = 0; rg < 2; ++rg) {
        int rb = r0 + rg * 16 + quad * 4;
#pragma unroll
        for (int reg = 0; reg < 4; ++reg) {
            int row = rb + reg;
            if (row < N) {
                float s = dins[row - d0];
#pragma unroll
                for (int cg = 0; cg < 8; ++cg)
                    t8[((size_t)cg * (N + 1) + row) * 16 + m] =
                        bf16r(acc[rg][cg][reg] * s);
            }
        }
    }

    // zero pad row N of each slice (replaces memset dispatch)
    if (r == NR - 1 && tid < 16) {
        int sl = tid >> 1, half = tid & 1;
        uint4 z = {0u, 0u, 0u, 0u};
        *(uint4*)(t8 + ((size_t)sl * (N + 1) + N) * 16 + half * 8) = z;
    }
}

// R17/R18 agg1: XCD-local slice gather. Slice sl = blockIdx&7 (round-robin
// -> one XCD owns one 3.2MB t8 slice, L2-resident). Wave per node per slice:
// 8 edges x 8 feature-lanes per load instr (idx shfl-broadcast, no LDS).
// Partial dot (relu separable across features) -> q8[sl][node].
__global__ __launch_bounds__(256) void k_agg1(
    const unsigned short* __restrict__ t8, const float* __restrict__ dinv,
    const int* __restrict__ rps, const int* __restrict__ rpe,
    const int* __restrict__ srt, const float* __restrict__ b1,
    const float* __restrict__ w2l, float* __restrict__ q8, int N, int gstride)
{
    int wave = threadIdx.x >> 6, lane = threadIdx.x & 63;
    int sl = blockIdx.x & 7;
    int wg = (blockIdx.x >> 3) * 4 + wave;     // wave id within slice group
    int f2 = lane & 7;                          // feature-pair index
    const unsigned short* tbase = t8 + (size_t)sl * (N + 1) * 16 + f2 * 2;
    float2 bb = *(const float2*)(b1 + sl * 16 + f2 * 2);
    float2 ww = *(const float2*)(w2l + sl * 16 + f2 * 2);
    float* qout = q8 + (size_t)sl * N;

    for (int node = wg; node < N; node += gstride) {
        int s0 = rps[node], s1 = rpe[node];
        int deg = s1 - s0;
        int vdeg = deg < 63 ? deg : 63;
        int idx = N;                            // pad -> zero row
        if (lane < vdeg) idx = srt[s0 + lane];
        else if (lane == vdeg) idx = node;      // self loop
        float a0 = 0.0f, a1 = 0.0f;
        int nb = (vdeg + 8) >> 3;               // ceil((vdeg+1)/8)
        for (int b = 0; b < nb; ++b) {
            int id = __shfl(idx, (b << 3) + (lane >> 3));
            unsigned u = *(const unsigned*)(tbase + (size_t)id * 16);
            a0 += bff((unsigned short)(u & 0xffff));
            a1 += bff((unsigned short)(u >> 16));
        }
        if (deg > 63) {                         // rare overflow path
            for (int e = s0 + 63; e < s1; ++e) {
                int id = srt[e];
                if (lane < 8) {
                    unsigned u = *(const unsigned*)(tbase + (size_t)id * 16);
                    a0 += bff((unsigned short)(u & 0xffff));
                    a1 += bff((unsigned short)(u >> 16));
                }
            }
        }
        // reduce over the 8 edge-slot groups (lane bits 3..5)
        a0 += __shfl_xor(a0, 8);  a1 += __shfl_xor(a1, 8);
        a0 += __shfl_xor(a0, 16); a1 += __shfl_xor(a1, 16);
        a0 += __shfl_xor(a0, 32); a1 += __shfl_xor(a1, 32);
        float di = dinv[node];
        float h0 = fmaxf(fmaf(a0, di, bb.x), 0.0f);
        float h1 = fmaxf(fmaf(a1, di, bb.y), 0.0f);
        float pr = h0 * ww.x + h1 * ww.y;
        // reduce over the 8 feature lanes (lane bits 0..2)
        pr += __shfl_xor(pr, 1);
        pr += __shfl_xor(pr, 2);
        pr += __shfl_xor(pr, 4);
        if (lane == 0) qout[node] = pr * di;
    }
}

// q[v] = sum over slices of q8[sl][v]  (8 coalesced streams).
__global__ __launch_bounds__(256) void k_qred(
    const float* __restrict__ q8, float* __restrict__ q, int N)
{
    int i = blockIdx.x * 256 + threadIdx.x;
    if (i < N) {
        float s = 0.0f;
#pragma unroll
        for (int sl = 0; sl < 8; ++sl) s += q8[(size_t)sl * N + i];
        q[i] = s;
    }
}

// agg2: 16 lanes per node, no atomics -> per-node p[] (coalesced store).
__global__ __launch_bounds__(256) void k_agg2(
    const float* __restrict__ q, const float* __restrict__ dinv,
    const int* __restrict__ rps, const int* __restrict__ rpe,
    const int* __restrict__ srt, float* __restrict__ p, int N)
{
    int tid = blockIdx.x * 256 + threadIdx.x;
    int node = tid >> 4;
    int l = tid & 15;
    if (node >= N) return;
    int s0 = rps[node], s1 = rpe[node];
    float a = 0.0f;
    for (int e = s0 + l; e < s1; e += 16) a += q[srt[e]];
#pragma unroll
    for (int off = 8; off > 0; off >>= 1) a += __shfl_xor(a, off);
    if (l == 0) p[node] = dinv[node] * (a + q[node]);
}

// pool: one wave per graph; batch sorted -> binary-search segment,
// coalesced sum. out[g] = mean + b2.Wl + bl.
__global__ __launch_bounds__(64) void k_pool(
    const float* __restrict__ p, const int* __restrict__ batch,
    const float* __restrict__ b2, const float* __restrict__ Wl,
    const float* __restrict__ bl, float* __restrict__ out, int N, int G)
{
    int g = blockIdx.x;
    int lane = threadIdx.x;
    __shared__ int sb[2];
    if (lane < 2) {
        int target = g + lane;
        int lo = 0, hi = N;
        while (lo < hi) {
            int mid = (lo + hi) >> 1;
            if (batch[mid] < target) lo = mid + 1; else hi = mid;
        }
        sb[lane] = lo;
    }
    __syncthreads();
    int s = sb[0], e = sb[1];
    float a = 0.0f;
    for (int i = s + lane; i < e; i += 64) a += p[i];
#pragma unroll
    for (int off = 32; off > 0; off >>= 1) a += __shfl_xor(a, off);
    if (lane == 0) {
        float c = 0.0f;
        for (int j = 0; j < 128; ++j) c = fmaf(b2[j], Wl[j], c);
        out[g] = a / fmaxf((float)(e - s), 1.0f) + c + bl[0];
    }
}

extern "C" void kernel_launch(void* const* d_in, const int* in_sizes, int n_in,
                              void* d_out, int out_size, void* d_ws, size_t ws_size,
                              hipStream_t stream)
{
    const float* x  = (const float*)d_in[0];
    const int*   ei = (const int*)d_in[1];
    // d_in[2] = edge_attr: unused by the reference
    const int*   batch = (const int*)d_in[3];
    const float* W1 = (const float*)d_in[4];
    const float* b1 = (const float*)d_in[5];
    const float* W2 = (const float*)d_in[6];
    const float* b2 = (const float*)d_in[7];
    const float* Wl = (const float*)d_in[8];
    const float* bl = (const float*)d_in[9];

    int N = in_sizes[0] / 128;
    int E = in_sizes[1] / 2;
    const int* src = ei;
    const int* dst = ei + E;

    char* ws = (char*)d_ws;
    size_t off = 0;
    auto alloc = [&](size_t bytes) -> void* {
        void* p = ws + off;
        off = (off + bytes + 255) & ~(size_t)255;
        return p;
    };
    int nchunks = (E + CHUNK - 1) / CHUNK;                   // 391
    int NR = (N + RW - 1) / RW;                              // 782 <= 1024
    unsigned short* t8 = (unsigned short*)alloc((size_t)8 * (N + 1) * 16 * 2); // slice-major bf16
    float* q8   = (float*)alloc((size_t)8 * N * 4);          // per-slice partial dots
    float* q    = (float*)alloc((size_t)N * 4);
    float* p    = (float*)alloc((size_t)N * 4);
    int*   srt  = (int*)alloc((size_t)NR * WCAP * 4);        // static windows (19.2MB)
    int*   part = (int*)alloc((size_t)nchunks * CHUNK * 4);  // packed (src<<7|d&127)
    int*   off_t= (int*)alloc((size_t)NR * nchunks * 4);
    int*   cnt_t= (int*)alloc((size_t)NR * nchunks * 4);
    float* dinv = (float*)alloc((size_t)N * 4);
    int*   rps  = (int*)alloc((size_t)N * 4);
    int*   rpe  = (int*)alloc((size_t)N * 4);
    float* w2l  = (float*)alloc(128 * 4);
    unsigned short* w1p = (unsigned short*)alloc(16384 * 2);
    (void)ws_size;

    k_partw<<<nchunks + 65, 256, 0, stream>>>(src, dst, part, off_t, cnt_t,
                                              W1, w1p, W2, Wl, w2l, E, nchunks, NR);
    k_build<<<NR, 256, 0, stream>>>(part, off_t, cnt_t, x, w1p, srt, rps, rpe,
                                    dinv, t8, nchunks, N, NR);
    int a1b = 2048;                      // 256 blocks per slice group
    k_agg1<<<a1b, 256, 0, stream>>>(t8, dinv, rps, rpe, srt, b1, w2l, q8, N,
                                    (a1b / 8) * 4);
    k_qred<<<(N + 255) / 256, 256, 0, stream>>>(q8, q, N);
    k_agg2<<<((size_t)N * 16 + 255) / 256, 256, 0, stream>>>(q, dinv, rps, rpe, srt, p, N);
    k_pool<<<512, 64, 0, stream>>>(p, batch, b2, Wl, bl, (float*)d_out, N, 512);
}

// Round 11
// 324.854 us; speedup vs baseline: 1.7602x; 1.3645x over previous
//
#include <hip/hip_runtime.h>

// GCN forward: 2× (GCNConv) + mean-pool + linear head. 5-dispatch pipeline:
//   k_partw: 782-chunk edge split into 782 node-ranges + W1 pack + w2l
//   k_build: per-range CSR build (LDS union w/ W1 stage) + t=(x@W1)*dinv MFMA
//   k_agg1:  one-wave-per-node quad-row gather (row-major bf16 t)
//   k_agg2:  16-lane/node gather of q (p scalars out)
//   k_pool:  sorted-batch segment mean + head
//
// R6: collapsed layer-2 q table: 785->636.  R8: bf16 MFMA mm.
// R10: XCD-local scatter: 617->583.  R11: bf16 t quad-rows: ->560.
// R12: atomic-free pool: 560->442.  R13: range-owned CSR build: 442->344.
// R14/R15: agg1 batching/persistent variants: NEUTRAL at 67us. FETCH pinned
//     188MB = 8 XCD x 25.6MB replication; 2.9 TB/s.
// R16: 11->5 dispatches: -3.5us -> launch gaps ~1us each; kernels sum ~330.
// R17: wave-coop build Phase A REGRESSED 60x MLP loss (195us).
// R18: slice-major t8 + XCD-local agg1: FETCH 188->46MB (capacity fix
//     WORKED) but 4B granule = 8x instr -> 183us. Row-major agg1@67us is
//     the efficient point; agg1 PARKED.
// R19: revert to R16 structure; attack latency-bound prep kernels:
//     (a) partw CHUNK 4096->2048 (782 blocks, 2x parallelism, 16KB LDS);
//     (b) build LDS union: stage/jbase (A-C) time-share 32KB with w1s (D)
//         -> 58->35KB LDS -> 2->4 blocks/CU.

typedef __attribute__((ext_vector_type(8))) short short8;
typedef __attribute__((ext_vector_type(4))) float f32x4;

#define CHUNK 2048   // edges per k_partw block (8 KB LDS stage, packed)
#define RW    128    // nodes per range (r = d >> 7)
#define SCAP  6144   // build LDS edge-stage capacity (3x expected 2048)
#define JCAP  1024   // build per-chunk base table capacity (>= nchunks=782)
#define WCAP  6144   // static srt window per range (3x Poisson(2048) mean)

__device__ __forceinline__ unsigned short bf16r(float f) {
    unsigned u = __float_as_uint(f);
    u += 0x7FFFu + ((u >> 16) & 1u);
    return (unsigned short)(u >> 16);
}

__device__ __forceinline__ float bff(unsigned short u) {
    return __uint_as_float((unsigned)u << 16);
}

// Fused: blocks [0,nchunks) = edge partition; blocks [nchunks,nchunks+64) =
// W1 bf16 pack; block nchunks+64 = w2l.
__global__ __launch_bounds__(256) void k_partw(
    const int* __restrict__ src, const int* __restrict__ dst,
    int* __restrict__ part, int* __restrict__ off_t, int* __restrict__ cnt_t,
    const float* __restrict__ W1, unsigned short* __restrict__ w1p,
    const float* __restrict__ W2, const float* __restrict__ Wl,
    float* __restrict__ w2l, int E, int nchunks, int NR)
{
    int tid = threadIdx.x;
    if (blockIdx.x >= nchunks) {
        int b = blockIdx.x - nchunks;
        if (b == 64) {
            if (tid < 128) {
                float s = 0.0f;
                for (int j = 0; j < 128; ++j) s = fmaf(W2[tid * 128 + j], Wl[j], s);
                w2l[tid] = s;
            }
            return;
        }
        int idx = b * 256 + tid;   // < 16384
        int k = idx >> 7, n = idx & 127;
        w1p[((k >> 3) * 128 + n) * 8 + (k & 7)] = bf16r(W1[idx]);
        return;
    }

    __shared__ int stage[CHUNK];         // 8 KB packed edges
    __shared__ int lcnt[1024];           // histogram / scan ping
    __shared__ int lscan[1024];          // scan pong
    int j = blockIdx.x;
    int base = j * CHUNK;

#pragma unroll
    for (int k = 0; k < 4; ++k) lcnt[tid + k * 256] = 0;
    __syncthreads();

    int mye[8], myr[8];
#pragma unroll
    for (int k = 0; k < 8; ++k) {
        int e = base + tid + (k << 8);
        bool ok = e < E;
        int s = ok ? src[e] : 0;
        int d = ok ? dst[e] : 0;
        int r = -1;
        if (ok) {
            r = d >> 7;
            atomicAdd(&lcnt[r], 1);
        }
        mye[k] = (s << 7) | (d & 127);
        myr[k] = r;
    }
    __syncthreads();

    // inclusive Hillis-Steele scan over 1024 (ping-pong)
    int* pa = lcnt;
    int* pb = lscan;
    for (int off = 1; off < 1024; off <<= 1) {
#pragma unroll
        for (int k = 0; k < 4; ++k) {
            int idx = tid + k * 256;
            int v = pa[idx];
            if (idx >= off) v += pa[idx - off];
            pb[idx] = v;
        }
        __syncthreads();
        int* tmp = pa; pa = pb; pb = tmp;
    }
    // pa = inclusive scan; pb free -> cursor array
    for (int i = tid; i < NR; i += 256) {
        int incl = pa[i];
        int excl = (i == 0) ? 0 : pa[i - 1];
        pb[i] = excl;
        off_t[(size_t)i * nchunks + j] = excl;
        cnt_t[(size_t)i * nchunks + j] = incl - excl;
    }
    __syncthreads();

#pragma unroll
    for (int k = 0; k < 8; ++k) {
        if (myr[k] >= 0) {
            int p = atomicAdd(&pb[myr[k]], 1);
            stage[p] = mye[k];
        }
    }
    __syncthreads();

    int valid = E - base; if (valid > CHUNK) valid = CHUNK;
    for (int i = tid; i < valid; i += 256)
        part[(size_t)base + i] = stage[i];
}

// Fused build: one block per range (128 nodes). LDS union: shu holds the
// edge stage + jbase during Phases A-C, then is reloaded as packed W1 for
// Phase D's MFMA (35KB total -> 4 blocks/CU, was 58KB -> 2).
// Phase A: per-thread chunk walks (256 independent chains; wave-coop R17
// version REGRESSED 60x). Phase B: LDS scan -> rps/rpe/dinv/cursors (static
// windows r*WCAP). Phase C: LDS-cursor scatter. Phase D: row-major bf16 t.
__global__ __launch_bounds__(256) void k_build(
    const int* __restrict__ part, const int* __restrict__ off_t,
    const int* __restrict__ cnt_t, const float* __restrict__ x,
    const unsigned short* __restrict__ w1p, int* __restrict__ srt,
    int* __restrict__ rps, int* __restrict__ rpe, float* __restrict__ dinv,
    unsigned short* __restrict__ t, int nchunks, int N, int NR)
{
    __shared__ int shu[8192];            // 32 KB union
    __shared__ int hist[RW], lcur[RW], s1[RW], s2[RW];
    __shared__ float dins[RW];
    __shared__ int cursor;
    int* stage = shu;                    // [0, SCAP)
    int* jbase = shu + SCAP;             // [SCAP, SCAP+JCAP)  (7168 <= 8192)
    int r = blockIdx.x;
    int tid = threadIdx.x;
    int d0 = r << 7;
    int width = N - d0; if (width > RW) width = RW;

    if (tid < RW) hist[tid] = 0;
    if (tid == 0) cursor = 0;
    __syncthreads();

    const int* orow = off_t + (size_t)r * nchunks;
    const int* crow = cnt_t + (size_t)r * nchunks;

    // Phase A: per-thread stage + histogram (256 independent chains)
    for (int j = tid; j < nchunks; j += 256) {
        int c = crow[j];
        if (c == 0) { jbase[j] = 0; continue; }
        int b = atomicAdd(&cursor, c);
        jbase[j] = b;
        const int* pp = part + (size_t)j * CHUNK + orow[j];
        for (int e = 0; e < c; ++e) {
            int ed = pp[e];
            int pos = b + e;
            if (pos < SCAP) stage[pos] = ed;
            atomicAdd(&hist[ed & 127], 1);
        }
    }
    __syncthreads();
    int total = cursor;

    // Phase B: exclusive scan of hist -> rps/rpe/dinv/cursors
    if (tid < RW) s1[tid] = hist[tid];
    __syncthreads();
    int* pa = s1; int* pb = s2;
    for (int off = 1; off < RW; off <<= 1) {
        if (tid < RW) {
            int v = pa[tid];
            if (tid >= off) v += pa[tid - off];
            pb[tid] = v;
        }
        __syncthreads();
        int* tmp = pa; pa = pb; pb = tmp;
    }
    int wbase = r * WCAP;
    if (tid < width) {
        int excl = (tid == 0) ? 0 : pa[tid - 1];
        int start = wbase + excl;
        int deg = hist[tid];
        rps[d0 + tid] = start;
        rpe[d0 + tid] = start + deg;
        lcur[tid] = start;
        float di = 1.0f / sqrtf((float)deg + 1.0f);
        dins[tid] = di;
        dinv[d0 + tid] = di;
    }
    __syncthreads();

    // Phase C: scatter from LDS stage into private window
    int lim = total < SCAP ? total : SCAP;
    for (int i = tid; i < lim; i += 256) {
        int ed = stage[i];
        int pos = atomicAdd(&lcur[ed & 127], 1);
        srt[pos] = ed >> 7;
    }
    // Overflow fallback (not expected: total ~2048 << SCAP, nchunks <= JCAP)
    if (total > SCAP) {
        for (int j = tid; j < nchunks; j += 256) {
            int c = crow[j];
            if (c == 0) continue;
            int b = jbase[j];
            int e0 = SCAP - b;
            if (e0 < 0) e0 = 0;
            if (e0 >= c) continue;
            const int* pp = part + (size_t)j * CHUNK + orow[j];
            for (int e = e0; e < c; ++e) {
                int ed = pp[e];
                int pos = atomicAdd(&lcur[ed & 127], 1);
                srt[pos] = ed >> 7;
            }
        }
    }
    __syncthreads();

    // Phase D: reload union as packed W1, then t rows = (x@W1)*dinv
    unsigned short* w1s = (unsigned short*)shu;
    {
        const uint4* s = (const uint4*)w1p;
        uint4* d = (uint4*)shu;
#pragma unroll
        for (int i = 0; i < 8; ++i) d[tid + i * 256] = s[tid + i * 256];
    }
    __syncthreads();

    int w = tid >> 6, lane = tid & 63;
    int m = lane & 15, quad = lane >> 4;
    int r0 = d0 + w * 32;

    f32x4 acc[2][8];
#pragma unroll
    for (int rg = 0; rg < 2; ++rg)
#pragma unroll
        for (int cg = 0; cg < 8; ++cg) {
            f32x4 z = {0.0f, 0.0f, 0.0f, 0.0f};
            acc[rg][cg] = z;
        }

#pragma unroll
    for (int ks = 0; ks < 4; ++ks) {
        int k0 = ks * 32 + quad * 8;
        short8 a[2];
#pragma unroll
        for (int rg = 0; rg < 2; ++rg) {
            int rr = r0 + rg * 16 + m;
            if (rr > N - 1) rr = N - 1;
            const float* ap = x + (size_t)rr * 128 + k0;
            float4 v0 = *(const float4*)ap;
            float4 v1 = *(const float4*)(ap + 4);
            short8 av;
            av[0] = (short)bf16r(v0.x); av[1] = (short)bf16r(v0.y);
            av[2] = (short)bf16r(v0.z); av[3] = (short)bf16r(v0.w);
            av[4] = (short)bf16r(v1.x); av[5] = (short)bf16r(v1.y);
            av[6] = (short)bf16r(v1.z); av[7] = (short)bf16r(v1.w);
            a[rg] = av;
        }
        int kc = ks * 4 + quad;
#pragma unroll
        for (int cg = 0; cg < 8; ++cg) {
            const short8* bp = (const short8*)&w1s[((size_t)kc * 128 + cg * 16 + m) * 8];
            short8 b = *bp;
            acc[0][cg] = __builtin_amdgcn_mfma_f32_16x16x32_bf16(a[0], b, acc[0][cg], 0, 0, 0);
            acc[1][cg] = __builtin_amdgcn_mfma_f32_16x16x32_bf16(a[1], b, acc[1][cg], 0, 0, 0);
        }
    }

    // C/D layout: col = lane&15, row = quad*4 + reg
#pragma unroll
    for (int rg = 0; rg < 2; ++rg) {
        int rb = r0 + rg * 16 + quad * 4;
#pragma unroll
        for (int reg = 0; reg < 4; ++reg) {
            int row = rb + reg;
            if (row < N) {
                float s = dins[row - d0];
#pragma unroll
                for (int cg = 0; cg < 8; ++cg)
                    t[(size_t)row * 128 + cg * 16 + m] = bf16r(acc[rg][cg][reg] * s);
            }
        }
    }

    // zero pad row N (replaces memset dispatch)
    if (r == NR - 1 && tid < 16) {
        uint4 z = {0u, 0u, 0u, 0u};
        ((uint4*)(t + (size_t)N * 128))[tid] = z;
    }
}

// agg1 (R11/R13 cascade, best measured 66.3us): one wave per node over
// bf16 t (256B rows). Quad-row short8 loads (1 vmem = 4 rows), 8/4/2/1
// batch cascade, indices LDS-broadcast, pads -> zero row N.
__global__ __launch_bounds__(256) void k_agg1(
    const unsigned short* __restrict__ t, const float* __restrict__ dinv,
    const int* __restrict__ rps, const int* __restrict__ rpe,
    const int* __restrict__ srt,
    const float* __restrict__ b1, const float* __restrict__ w2l,
    float* __restrict__ q, int N)
{
    __shared__ int shi[4][64];
    int wave = threadIdx.x >> 6;
    int lane = threadIdx.x & 63;
    int node = blockIdx.x * 4 + wave;
    if (node >= N) return;
    int s0 = rps[node], s1 = rpe[node];
    int deg = s1 - s0;
    int vdeg = deg < 63 ? deg : 63;

    int idx = N;                                // zero row (pad)
    if (lane < vdeg) idx = srt[s0 + lane];      // one vector load per node
    else if (lane == vdeg) idx = node;          // self-loop row
    shi[wave][lane] = idx;
    const int* shw = shi[wave];

    int r4 = lane >> 4;              // row within quad
    int c = lane & 15;               // 8-column slice
    const unsigned short* tc = t + c * 8;

    float a[8];
#pragma unroll
    for (int k = 0; k < 8; ++k) a[k] = 0.0f;

    int nrows = vdeg + 1;            // edges + self
    int nquads = (nrows + 3) >> 2;   // tail padded with zero rows
    int p = 0;

    while (p + 8 <= nquads) {
        short8 v[8];
#pragma unroll
        for (int j = 0; j < 8; ++j) {
            int id = shw[((p + j) << 2) + r4];
            v[j] = *(const short8*)(tc + (size_t)id * 128);
        }
#pragma unroll
        for (int j = 0; j < 8; ++j)
#pragma unroll
            for (int k = 0; k < 8; ++k)
                a[k] += bff((unsigned short)v[j][k]);
        p += 8;
    }
    if (p + 4 <= nquads) {
        short8 v[4];
#pragma unroll
        for (int j = 0; j < 4; ++j) {
            int id = shw[((p + j) << 2) + r4];
            v[j] = *(const short8*)(tc + (size_t)id * 128);
        }
#pragma unroll
        for (int j = 0; j < 4; ++j)
#pragma unroll
            for (int k = 0; k < 8; ++k)
                a[k] += bff((unsigned short)v[j][k]);
        p += 4;
    }
    if (p + 2 <= nquads) {
        short8 v[2];
#pragma unroll
        for (int j = 0; j < 2; ++j) {
            int id = shw[((p + j) << 2) + r4];
            v[j] = *(const short8*)(tc + (size_t)id * 128);
        }
#pragma unroll
        for (int j = 0; j < 2; ++j)
#pragma unroll
            for (int k = 0; k < 8; ++k)
                a[k] += bff((unsigned short)v[j][k]);
        p += 2;
    }
    if (p < nquads) {
        int id = shw[(p << 2) + r4];
        short8 v = *(const short8*)(tc + (size_t)id * 128);
#pragma unroll
        for (int k = 0; k < 8; ++k)
            a[k] += bff((unsigned short)v[k]);
    }
    if (deg > 63) {                 // rare overflow path (deg >= 64)
        for (int e = s0 + 63; e < s1; ++e) {
            int id = srt[e];
            short8 v = *(const short8*)(tc + (size_t)id * 128);
            if (r4 == 0)
#pragma unroll
                for (int k = 0; k < 8; ++k)
                    a[k] += bff((unsigned short)v[k]);
        }
    }

    // reduce across the 4 row-groups (lanes differing in bits 4,5)
#pragma unroll
    for (int k = 0; k < 8; ++k) {
        a[k] += __shfl_xor(a[k], 16);
        a[k] += __shfl_xor(a[k], 32);
    }

    float di = dinv[node];
    float4 b0 = *(const float4*)(b1 + c * 8);
    float4 b4 = *(const float4*)(b1 + c * 8 + 4);
    float4 w0 = *(const float4*)(w2l + c * 8);
    float4 w4 = *(const float4*)(w2l + c * 8 + 4);
    float pr = 0.0f;
    pr += fmaxf(fmaf(a[0], di, b0.x), 0.0f) * w0.x;
    pr += fmaxf(fmaf(a[1], di, b0.y), 0.0f) * w0.y;
    pr += fmaxf(fmaf(a[2], di, b0.z), 0.0f) * w0.z;
    pr += fmaxf(fmaf(a[3], di, b0.w), 0.0f) * w0.w;
    pr += fmaxf(fmaf(a[4], di, b4.x), 0.0f) * w4.x;
    pr += fmaxf(fmaf(a[5], di, b4.y), 0.0f) * w4.y;
    pr += fmaxf(fmaf(a[6], di, b4.z), 0.0f) * w4.z;
    pr += fmaxf(fmaf(a[7], di, b4.w), 0.0f) * w4.w;
#pragma unroll
    for (int off = 8; off > 0; off >>= 1) pr += __shfl_xor(pr, off);
    if (lane == 0) q[node] = pr * di;
}

// agg2: 16 lanes per node, no atomics -> per-node p[] (coalesced store).
__global__ __launch_bounds__(256) void k_agg2(
    const float* __restrict__ q, const float* __restrict__ dinv,
    const int* __restrict__ rps, const int* __restrict__ rpe,
    const int* __restrict__ srt, float* __restrict__ p, int N)
{
    int tid = blockIdx.x * 256 + threadIdx.x;
    int node = tid >> 4;
    int l = tid & 15;
    if (node >= N) return;
    int s0 = rps[node], s1 = rpe[node];
    float a = 0.0f;
    for (int e = s0 + l; e < s1; e += 16) a += q[srt[e]];
#pragma unroll
    for (int off = 8; off > 0; off >>= 1) a += __shfl_xor(a, off);
    if (l == 0) p[node] = dinv[node] * (a + q[node]);
}

// pool: one wave per graph; batch sorted -> binary-search segment,
// coalesced sum. out[g] = mean + b2.Wl + bl.
__global__ __launch_bounds__(64) void k_pool(
    const float* __restrict__ p, const int* __restrict__ batch,
    const float* __restrict__ b2, const float* __restrict__ Wl,
    const float* __restrict__ bl, float* __restrict__ out, int N, int G)
{
    int g = blockIdx.x;
    int lane = threadIdx.x;
    __shared__ int sb[2];
    if (lane < 2) {
        int target = g + lane;
        int lo = 0, hi = N;
        while (lo < hi) {
            int mid = (lo + hi) >> 1;
            if (batch[mid] < target) lo = mid + 1; else hi = mid;
        }
        sb[lane] = lo;
    }
    __syncthreads();
    int s = sb[0], e = sb[1];
    float a = 0.0f;
    for (int i = s + lane; i < e; i += 64) a += p[i];
#pragma unroll
    for (int off = 32; off > 0; off >>= 1) a += __shfl_xor(a, off);
    if (lane == 0) {
        float c = 0.0f;
        for (int j = 0; j < 128; ++j) c = fmaf(b2[j], Wl[j], c);
        out[g] = a / fmaxf((float)(e - s), 1.0f) + c + bl[0];
    }
}

extern "C" void kernel_launch(void* const* d_in, const int* in_sizes, int n_in,
                              void* d_out, int out_size, void* d_ws, size_t ws_size,
                              hipStream_t stream)
{
    const float* x  = (const float*)d_in[0];
    const int*   ei = (const int*)d_in[1];
    // d_in[2] = edge_attr: unused by the reference
    const int*   batch = (const int*)d_in[3];
    const float* W1 = (const float*)d_in[4];
    const float* b1 = (const float*)d_in[5];
    const float* W2 = (const float*)d_in[6];
    const float* b2 = (const float*)d_in[7];
    const float* Wl = (const float*)d_in[8];
    const float* bl = (const float*)d_in[9];

    int N = in_sizes[0] / 128;
    int E = in_sizes[1] / 2;
    const int* src = ei;
    const int* dst = ei + E;

    char* ws = (char*)d_ws;
    size_t off = 0;
    auto alloc = [&](size_t bytes) -> void* {
        void* p = ws + off;
        off = (off + bytes + 255) & ~(size_t)255;
        return p;
    };
    int nchunks = (E + CHUNK - 1) / CHUNK;                   // 782
    int NR = (N + RW - 1) / RW;                              // 782 <= 1024
    unsigned short* t = (unsigned short*)alloc((size_t)(N + 1) * 128 * 2); // bf16 t + zero row
    float* q    = (float*)alloc((size_t)N * 4);
    float* p    = (float*)alloc((size_t)N * 4);
    int*   srt  = (int*)alloc((size_t)NR * WCAP * 4);        // static windows (19.2MB)
    int*   part = (int*)alloc((size_t)nchunks * CHUNK * 4);  // packed (src<<7|d&127)
    int*   off_t= (int*)alloc((size_t)NR * nchunks * 4);     // 2.45MB
    int*   cnt_t= (int*)alloc((size_t)NR * nchunks * 4);
    float* dinv = (float*)alloc((size_t)N * 4);
    int*   rps  = (int*)alloc((size_t)N * 4);
    int*   rpe  = (int*)alloc((size_t)N * 4);
    float* w2l  = (float*)alloc(128 * 4);
    unsigned short* w1p = (unsigned short*)alloc(16384 * 2);
    (void)ws_size;

    k_partw<<<nchunks + 65, 256, 0, stream>>>(src, dst, part, off_t, cnt_t,
                                              W1, w1p, W2, Wl, w2l, E, nchunks, NR);
    k_build<<<NR, 256, 0, stream>>>(part, off_t, cnt_t, x, w1p, srt, rps, rpe,
                                    dinv, t, nchunks, N, NR);
    k_agg1<<<(N + 3) / 4, 256, 0, stream>>>(t, dinv, rps, rpe, srt, b1, w2l, q, N);
    k_agg2<<<((size_t)N * 16 + 255) / 256, 256, 0, stream>>>(q, dinv, rps, rpe, srt, p, N);
    k_pool<<<512, 64, 0, stream>>>(p, batch, b2, Wl, bl, (float*)d_out, N, 512);
}

// Round 12
// 315.522 us; speedup vs baseline: 1.8123x; 1.0296x over previous
//
#include <hip/hip_runtime.h>

// GCN forward: 2× (GCNConv) + mean-pool + linear head. 5-dispatch pipeline:
//   k_partw: 782-chunk edge split into 782 node-ranges + W1 pack + w2l
//   k_build: per-range CSR build (LDS union w/ W1 stage) + t=(x@W1)*dinv MFMA
//   k_agg1:  DUAL-node-per-wave quad-row gather (row-major bf16 t)
//   k_agg2:  16-lane/node gather of q (p scalars out)
//   k_pool:  sorted-batch segment mean + head
//
// R6: collapsed layer-2 q table: 785->636.  R8: bf16 MFMA mm.
// R10: XCD-local scatter: 617->583.  R11: bf16 t quad-rows: ->560.
// R12: atomic-free pool: 560->442.  R13: range-owned CSR build: 442->344.
// R14/R15: agg1 always-8 / persistent variants: NEUTRAL at 67us.
// R16: 11->5 dispatches: -3.5us (launch gaps ~1us, not the hidden time).
// R17: wave-coop build Phase A REGRESSED (60x MLP loss).
// R18: slice-major t8 + XCD agg1: FETCH 188->46MB but 8x instr -> 183us.
//     Row-major agg1 is the efficient point.
// R19: partw CHUNK->2048 + build LDS union: 332->325.
// R20: agg1 line-rate analysis: f32 (R11) sustained ~57 lines/us @occ 65%;
//     bf16 only ~44 @occ 46% -- same lines/instr, same 8KB in flight/wave.
//     Limit = outstanding misses. Dual-node per wave: 16 quad-loads (16KB)
//     in flight per round from 2 independent streams; always-full batches
//     (pads -> L1-hot zero row, proven free in R14). In-flight bytes/CU
//     ~2.7x. Also the probe for real-vs-overhead time attribution.

typedef __attribute__((ext_vector_type(8))) short short8;
typedef __attribute__((ext_vector_type(4))) float f32x4;

#define CHUNK 2048   // edges per k_partw block (8 KB LDS stage, packed)
#define RW    128    // nodes per range (r = d >> 7)
#define SCAP  6144   // build LDS edge-stage capacity (3x expected 2048)
#define JCAP  1024   // build per-chunk base table capacity (>= nchunks=782)
#define WCAP  6144   // static srt window per range (3x Poisson(2048) mean)

__device__ __forceinline__ unsigned short bf16r(float f) {
    unsigned u = __float_as_uint(f);
    u += 0x7FFFu + ((u >> 16) & 1u);
    return (unsigned short)(u >> 16);
}

__device__ __forceinline__ float bff(unsigned short u) {
    return __uint_as_float((unsigned)u << 16);
}

// Fused: blocks [0,nchunks) = edge partition; blocks [nchunks,nchunks+64) =
// W1 bf16 pack; block nchunks+64 = w2l.
__global__ __launch_bounds__(256) void k_partw(
    const int* __restrict__ src, const int* __restrict__ dst,
    int* __restrict__ part, int* __restrict__ off_t, int* __restrict__ cnt_t,
    const float* __restrict__ W1, unsigned short* __restrict__ w1p,
    const float* __restrict__ W2, const float* __restrict__ Wl,
    float* __restrict__ w2l, int E, int nchunks, int NR)
{
    int tid = threadIdx.x;
    if (blockIdx.x >= nchunks) {
        int b = blockIdx.x - nchunks;
        if (b == 64) {
            if (tid < 128) {
                float s = 0.0f;
                for (int j = 0; j < 128; ++j) s = fmaf(W2[tid * 128 + j], Wl[j], s);
                w2l[tid] = s;
            }
            return;
        }
        int idx = b * 256 + tid;   // < 16384
        int k = idx >> 7, n = idx & 127;
        w1p[((k >> 3) * 128 + n) * 8 + (k & 7)] = bf16r(W1[idx]);
        return;
    }

    __shared__ int stage[CHUNK];         // 8 KB packed edges
    __shared__ int lcnt[1024];           // histogram / scan ping
    __shared__ int lscan[1024];          // scan pong
    int j = blockIdx.x;
    int base = j * CHUNK;

#pragma unroll
    for (int k = 0; k < 4; ++k) lcnt[tid + k * 256] = 0;
    __syncthreads();

    int mye[8], myr[8];
#pragma unroll
    for (int k = 0; k < 8; ++k) {
        int e = base + tid + (k << 8);
        bool ok = e < E;
        int s = ok ? src[e] : 0;
        int d = ok ? dst[e] : 0;
        int r = -1;
        if (ok) {
            r = d >> 7;
            atomicAdd(&lcnt[r], 1);
        }
        mye[k] = (s << 7) | (d & 127);
        myr[k] = r;
    }
    __syncthreads();

    // inclusive Hillis-Steele scan over 1024 (ping-pong)
    int* pa = lcnt;
    int* pb = lscan;
    for (int off = 1; off < 1024; off <<= 1) {
#pragma unroll
        for (int k = 0; k < 4; ++k) {
            int idx = tid + k * 256;
            int v = pa[idx];
            if (idx >= off) v += pa[idx - off];
            pb[idx] = v;
        }
        __syncthreads();
        int* tmp = pa; pa = pb; pb = tmp;
    }
    // pa = inclusive scan; pb free -> cursor array
    for (int i = tid; i < NR; i += 256) {
        int incl = pa[i];
        int excl = (i == 0) ? 0 : pa[i - 1];
        pb[i] = excl;
        off_t[(size_t)i * nchunks + j] = excl;
        cnt_t[(size_t)i * nchunks + j] = incl - excl;
    }
    __syncthreads();

#pragma unroll
    for (int k = 0; k < 8; ++k) {
        if (myr[k] >= 0) {
            int p = atomicAdd(&pb[myr[k]], 1);
            stage[p] = mye[k];
        }
    }
    __syncthreads();

    int valid = E - base; if (valid > CHUNK) valid = CHUNK;
    for (int i = tid; i < valid; i += 256)
        part[(size_t)base + i] = stage[i];
}

// Fused build: one block per range (128 nodes). LDS union: shu holds the
// edge stage + jbase during Phases A-C, then is reloaded as packed W1 for
// Phase D's MFMA (35KB total -> 4 blocks/CU).
// Phase A: per-thread chunk walks (256 independent chains). Phase B: LDS
// scan -> rps/rpe/dinv/cursors (static windows r*WCAP). Phase C: LDS-cursor
// scatter. Phase D: row-major bf16 t.
__global__ __launch_bounds__(256) void k_build(
    const int* __restrict__ part, const int* __restrict__ off_t,
    const int* __restrict__ cnt_t, const float* __restrict__ x,
    const unsigned short* __restrict__ w1p, int* __restrict__ srt,
    int* __restrict__ rps, int* __restrict__ rpe, float* __restrict__ dinv,
    unsigned short* __restrict__ t, int nchunks, int N, int NR)
{
    __shared__ int shu[8192];            // 32 KB union
    __shared__ int hist[RW], lcur[RW], s1[RW], s2[RW];
    __shared__ float dins[RW];
    __shared__ int cursor;
    int* stage = shu;                    // [0, SCAP)
    int* jbase = shu + SCAP;             // [SCAP, SCAP+JCAP)  (7168 <= 8192)
    int r = blockIdx.x;
    int tid = threadIdx.x;
    int d0 = r << 7;
    int width = N - d0; if (width > RW) width = RW;

    if (tid < RW) hist[tid] = 0;
    if (tid == 0) cursor = 0;
    __syncthreads();

    const int* orow = off_t + (size_t)r * nchunks;
    const int* crow = cnt_t + (size_t)r * nchunks;

    // Phase A: per-thread stage + histogram (256 independent chains)
    for (int j = tid; j < nchunks; j += 256) {
        int c = crow[j];
        if (c == 0) { jbase[j] = 0; continue; }
        int b = atomicAdd(&cursor, c);
        jbase[j] = b;
        const int* pp = part + (size_t)j * CHUNK + orow[j];
        for (int e = 0; e < c; ++e) {
            int ed = pp[e];
            int pos = b + e;
            if (pos < SCAP) stage[pos] = ed;
            atomicAdd(&hist[ed & 127], 1);
        }
    }
    __syncthreads();
    int total = cursor;

    // Phase B: exclusive scan of hist -> rps/rpe/dinv/cursors
    if (tid < RW) s1[tid] = hist[tid];
    __syncthreads();
    int* pa = s1; int* pb = s2;
    for (int off = 1; off < RW; off <<= 1) {
        if (tid < RW) {
            int v = pa[tid];
            if (tid >= off) v += pa[tid - off];
            pb[tid] = v;
        }
        __syncthreads();
        int* tmp = pa; pa = pb; pb = tmp;
    }
    int wbase = r * WCAP;
    if (tid < width) {
        int excl = (tid == 0) ? 0 : pa[tid - 1];
        int start = wbase + excl;
        int deg = hist[tid];
        rps[d0 + tid] = start;
        rpe[d0 + tid] = start + deg;
        lcur[tid] = start;
        float di = 1.0f / sqrtf((float)deg + 1.0f);
        dins[tid] = di;
        dinv[d0 + tid] = di;
    }
    __syncthreads();

    // Phase C: scatter from LDS stage into private window
    int lim = total < SCAP ? total : SCAP;
    for (int i = tid; i < lim; i += 256) {
        int ed = stage[i];
        int pos = atomicAdd(&lcur[ed & 127], 1);
        srt[pos] = ed >> 7;
    }
    // Overflow fallback (not expected: total ~2048 << SCAP, nchunks <= JCAP)
    if (total > SCAP) {
        for (int j = tid; j < nchunks; j += 256) {
            int c = crow[j];
            if (c == 0) continue;
            int b = jbase[j];
            int e0 = SCAP - b;
            if (e0 < 0) e0 = 0;
            if (e0 >= c) continue;
            const int* pp = part + (size_t)j * CHUNK + orow[j];
            for (int e = e0; e < c; ++e) {
                int ed = pp[e];
                int pos = atomicAdd(&lcur[ed & 127], 1);
                srt[pos] = ed >> 7;
            }
        }
    }
    __syncthreads();

    // Phase D: reload union as packed W1, then t rows = (x@W1)*dinv
    unsigned short* w1s = (unsigned short*)shu;
    {
        const uint4* s = (const uint4*)w1p;
        uint4* d = (uint4*)shu;
#pragma unroll
        for (int i = 0; i < 8; ++i) d[tid + i * 256] = s[tid + i * 256];
    }
    __syncthreads();

    int w = tid >> 6, lane = tid & 63;
    int m = lane & 15, quad = lane >> 4;
    int r0 = d0 + w * 32;

    f32x4 acc[2][8];
#pragma unroll
    for (int rg = 0; rg < 2; ++rg)
#pragma unroll
        for (int cg = 0; cg < 8; ++cg) {
            f32x4 z = {0.0f, 0.0f, 0.0f, 0.0f};
            acc[rg][cg] = z;
        }

#pragma unroll
    for (int ks = 0; ks < 4; ++ks) {
        int k0 = ks * 32 + quad * 8;
        short8 a[2];
#pragma unroll
        for (int rg = 0; rg < 2; ++rg) {
            int rr = r0 + rg * 16 + m;
            if (rr > N - 1) rr = N - 1;
            const float* ap = x + (size_t)rr * 128 + k0;
            float4 v0 = *(const float4*)ap;
            float4 v1 = *(const float4*)(ap + 4);
            short8 av;
            av[0] = (short)bf16r(v0.x); av[1] = (short)bf16r(v0.y);
            av[2] = (short)bf16r(v0.z); av[3] = (short)bf16r(v0.w);
            av[4] = (short)bf16r(v1.x); av[5] = (short)bf16r(v1.y);
            av[6] = (short)bf16r(v1.z); av[7] = (short)bf16r(v1.w);
            a[rg] = av;
        }
        int kc = ks * 4 + quad;
#pragma unroll
        for (int cg = 0; cg < 8; ++cg) {
            const short8* bp = (const short8*)&w1s[((size_t)kc * 128 + cg * 16 + m) * 8];
            short8 b = *bp;
            acc[0][cg] = __builtin_amdgcn_mfma_f32_16x16x32_bf16(a[0], b, acc[0][cg], 0, 0, 0);
            acc[1][cg] = __builtin_amdgcn_mfma_f32_16x16x32_bf16(a[1], b, acc[1][cg], 0, 0, 0);
        }
    }

    // C/D layout: col = lane&15, row = quad*4 + reg
#pragma unroll
    for (int rg = 0; rg < 2; ++rg) {
        int rb = r0 + rg * 16 + quad * 4;
#pragma unroll
        for (int reg = 0; reg < 4; ++reg) {
            int row = rb + reg;
            if (row < N) {
                float s = dins[row - d0];
#pragma unroll
                for (int cg = 0; cg < 8; ++cg)
                    t[(size_t)row * 128 + cg * 16 + m] = bf16r(acc[rg][cg][reg] * s);
            }
        }
    }

    // zero pad row N (replaces memset dispatch)
    if (r == NR - 1 && tid < 16) {
        uint4 z = {0u, 0u, 0u, 0u};
        ((uint4*)(t + (size_t)N * 128))[tid] = z;
    }
}

// R20 agg1: DUAL node per wave. Both index lists staged in LDS, gather loop
// issues 16 quad-row short8 loads (16KB, 2 independent streams) per round
// before consuming. Always-full batches (pads -> L1-hot zero row N).
__global__ __launch_bounds__(256) void k_agg1(
    const unsigned short* __restrict__ t, const float* __restrict__ dinv,
    const int* __restrict__ rps, const int* __restrict__ rpe,
    const int* __restrict__ srt,
    const float* __restrict__ b1, const float* __restrict__ w2l,
    float* __restrict__ q, int N)
{
    __shared__ int shi[4][2][64];
    int wave = threadIdx.x >> 6;
    int lane = threadIdx.x & 63;
    int n0 = blockIdx.x * 8 + wave * 2;
    if (n0 >= N) return;
    int n1 = n0 + 1;
    bool has1 = n1 < N;

    int s00 = rps[n0], s01 = rpe[n0];
    int s10 = has1 ? rps[n1] : 0, s11 = has1 ? rpe[n1] : 0;
    int deg0 = s01 - s00, deg1 = s11 - s10;
    int vd0 = deg0 < 63 ? deg0 : 63;
    int vd1 = deg1 < 63 ? deg1 : 63;

    int i0 = N, i1 = N;                         // pads -> zero row
    if (lane < vd0) i0 = srt[s00 + lane];
    else if (lane == vd0) i0 = n0;              // self loop
    if (has1) {
        if (lane < vd1) i1 = srt[s10 + lane];
        else if (lane == vd1) i1 = n1;
    }
    shi[wave][0][lane] = i0;
    shi[wave][1][lane] = i1;
    const int* w0i = shi[wave][0];
    const int* w1i = shi[wave][1];

    int r4 = lane >> 4;              // row within quad
    int c = lane & 15;               // 8-column slice
    const unsigned short* tc = t + c * 8;

    float a0[8], a1[8];
#pragma unroll
    for (int k = 0; k < 8; ++k) { a0[k] = 0.0f; a1[k] = 0.0f; }

    int nq0 = (vd0 + 4) >> 2;        // ceil((vd0+1)/4), 1..16
    int nq1 = has1 ? ((vd1 + 4) >> 2) : 0;
    int nq = nq0 > nq1 ? nq0 : nq1;
    int p = 0;
    do {
        short8 v0[8], v1[8];
#pragma unroll
        for (int j = 0; j < 8; ++j) {
            int id = w0i[((p + j) << 2) + r4];
            v0[j] = *(const short8*)(tc + (size_t)id * 128);
        }
#pragma unroll
        for (int j = 0; j < 8; ++j) {
            int id = w1i[((p + j) << 2) + r4];
            v1[j] = *(const short8*)(tc + (size_t)id * 128);
        }
#pragma unroll
        for (int j = 0; j < 8; ++j)
#pragma unroll
            for (int k = 0; k < 8; ++k)
                a0[k] += bff((unsigned short)v0[j][k]);
#pragma unroll
        for (int j = 0; j < 8; ++j)
#pragma unroll
            for (int k = 0; k < 8; ++k)
                a1[k] += bff((unsigned short)v1[j][k]);
        p += 8;
    } while (p < nq);

    if (deg0 > 63) {                 // rare overflow (deg >= 64)
        for (int e = s00 + 63; e < s01; ++e) {
            int id = srt[e];
            short8 v = *(const short8*)(tc + (size_t)id * 128);
            if (r4 == 0)
#pragma unroll
                for (int k = 0; k < 8; ++k)
                    a0[k] += bff((unsigned short)v[k]);
        }
    }
    if (has1 && deg1 > 63) {
        for (int e = s10 + 63; e < s11; ++e) {
            int id = srt[e];
            short8 v = *(const short8*)(tc + (size_t)id * 128);
            if (r4 == 0)
#pragma unroll
                for (int k = 0; k < 8; ++k)
                    a1[k] += bff((unsigned short)v[k]);
        }
    }

    // reduce across the 4 row-groups (lanes differing in bits 4,5)
#pragma unroll
    for (int k = 0; k < 8; ++k) {
        a0[k] += __shfl_xor(a0[k], 16);
        a0[k] += __shfl_xor(a0[k], 32);
        a1[k] += __shfl_xor(a1[k], 16);
        a1[k] += __shfl_xor(a1[k], 32);
    }

    float4 b0 = *(const float4*)(b1 + c * 8);
    float4 b4 = *(const float4*)(b1 + c * 8 + 4);
    float4 w0 = *(const float4*)(w2l + c * 8);
    float4 w4 = *(const float4*)(w2l + c * 8 + 4);

    {
        float di = dinv[n0];
        float pr = 0.0f;
        pr += fmaxf(fmaf(a0[0], di, b0.x), 0.0f) * w0.x;
        pr += fmaxf(fmaf(a0[1], di, b0.y), 0.0f) * w0.y;
        pr += fmaxf(fmaf(a0[2], di, b0.z), 0.0f) * w0.z;
        pr += fmaxf(fmaf(a0[3], di, b0.w), 0.0f) * w0.w;
        pr += fmaxf(fmaf(a0[4], di, b4.x), 0.0f) * w4.x;
        pr += fmaxf(fmaf(a0[5], di, b4.y), 0.0f) * w4.y;
        pr += fmaxf(fmaf(a0[6], di, b4.z), 0.0f) * w4.z;
        pr += fmaxf(fmaf(a0[7], di, b4.w), 0.0f) * w4.w;
#pragma unroll
        for (int off = 8; off > 0; off >>= 1) pr += __shfl_xor(pr, off);
        if (lane == 0) q[n0] = pr * di;
    }
    if (has1) {
        float di = dinv[n1];
        float pr = 0.0f;
        pr += fmaxf(fmaf(a1[0], di, b0.x), 0.0f) * w0.x;
        pr += fmaxf(fmaf(a1[1], di, b0.y), 0.0f) * w0.y;
        pr += fmaxf(fmaf(a1[2], di, b0.z), 0.0f) * w0.z;
        pr += fmaxf(fmaf(a1[3], di, b0.w), 0.0f) * w0.w;
        pr += fmaxf(fmaf(a1[4], di, b4.x), 0.0f) * w4.x;
        pr += fmaxf(fmaf(a1[5], di, b4.y), 0.0f) * w4.y;
        pr += fmaxf(fmaf(a1[6], di, b4.z), 0.0f) * w4.z;
        pr += fmaxf(fmaf(a1[7], di, b4.w), 0.0f) * w4.w;
#pragma unroll
        for (int off = 8; off > 0; off >>= 1) pr += __shfl_xor(pr, off);
        if (lane == 0) q[n1] = pr * di;
    }
}

// agg2: 16 lanes per node, no atomics -> per-node p[] (coalesced store).
__global__ __launch_bounds__(256) void k_agg2(
    const float* __restrict__ q, const float* __restrict__ dinv,
    const int* __restrict__ rps, const int* __restrict__ rpe,
    const int* __restrict__ srt, float* __restrict__ p, int N)
{
    int tid = blockIdx.x * 256 + threadIdx.x;
    int node = tid >> 4;
    int l = tid & 15;
    if (node >= N) return;
    int s0 = rps[node], s1 = rpe[node];
    float a = 0.0f;
    for (int e = s0 + l; e < s1; e += 16) a += q[srt[e]];
#pragma unroll
    for (int off = 8; off > 0; off >>= 1) a += __shfl_xor(a, off);
    if (l == 0) p[node] = dinv[node] * (a + q[node]);
}

// pool: one wave per graph; batch sorted -> binary-search segment,
// coalesced sum. out[g] = mean + b2.Wl + bl.
__global__ __launch_bounds__(64) void k_pool(
    const float* __restrict__ p, const int* __restrict__ batch,
    const float* __restrict__ b2, const float* __restrict__ Wl,
    const float* __restrict__ bl, float* __restrict__ out, int N, int G)
{
    int g = blockIdx.x;
    int lane = threadIdx.x;
    __shared__ int sb[2];
    if (lane < 2) {
        int target = g + lane;
        int lo = 0, hi = N;
        while (lo < hi) {
            int mid = (lo + hi) >> 1;
            if (batch[mid] < target) lo = mid + 1; else hi = mid;
        }
        sb[lane] = lo;
    }
    __syncthreads();
    int s = sb[0], e = sb[1];
    float a = 0.0f;
    for (int i = s + lane; i < e; i += 64) a += p[i];
#pragma unroll
    for (int off = 32; off > 0; off >>= 1) a += __shfl_xor(a, off);
    if (lane == 0) {
        float c = 0.0f;
        for (int j = 0; j < 128; ++j) c = fmaf(b2[j], Wl[j], c);
        out[g] = a / fmaxf((float)(e - s), 1.0f) + c + bl[0];
    }
}

extern "C" void kernel_launch(void* const* d_in, const int* in_sizes, int n_in,
                              void* d_out, int out_size, void* d_ws, size_t ws_size,
                              hipStream_t stream)
{
    const float* x  = (const float*)d_in[0];
    const int*   ei = (const int*)d_in[1];
    // d_in[2] = edge_attr: unused by the reference
    const int*   batch = (const int*)d_in[3];
    const float* W1 = (const float*)d_in[4];
    const float* b1 = (const float*)d_in[5];
    const float* W2 = (const float*)d_in[6];
    const float* b2 = (const float*)d_in[7];
    const float* Wl = (const float*)d_in[8];
    const float* bl = (const float*)d_in[9];

    int N = in_sizes[0] / 128;
    int E = in_sizes[1] / 2;
    const int* src = ei;
    const int* dst = ei + E;

    char* ws = (char*)d_ws;
    size_t off = 0;
    auto alloc = [&](size_t bytes) -> void* {
        void* p = ws + off;
        off = (off + bytes + 255) & ~(size_t)255;
        return p;
    };
    int nchunks = (E + CHUNK - 1) / CHUNK;                   // 782
    int NR = (N + RW - 1) / RW;                              // 782 <= 1024
    unsigned short* t = (unsigned short*)alloc((size_t)(N + 1) * 128 * 2); // bf16 t + zero row
    float* q    = (float*)alloc((size_t)N * 4);
    float* p    = (float*)alloc((size_t)N * 4);
    int*   srt  = (int*)alloc((size_t)NR * WCAP * 4);        // static windows (19.2MB)
    int*   part = (int*)alloc((size_t)nchunks * CHUNK * 4);  // packed (src<<7|d&127)
    int*   off_t= (int*)alloc((size_t)NR * nchunks * 4);     // 2.45MB
    int*   cnt_t= (int*)alloc((size_t)NR * nchunks * 4);
    float* dinv = (float*)alloc((size_t)N * 4);
    int*   rps  = (int*)alloc((size_t)N * 4);
    int*   rpe  = (int*)alloc((size_t)N * 4);
    float* w2l  = (float*)alloc(128 * 4);
    unsigned short* w1p = (unsigned short*)alloc(16384 * 2);
    (void)ws_size;

    k_partw<<<nchunks + 65, 256, 0, stream>>>(src, dst, part, off_t, cnt_t,
                                              W1, w1p, W2, Wl, w2l, E, nchunks, NR);
    k_build<<<NR, 256, 0, stream>>>(part, off_t, cnt_t, x, w1p, srt, rps, rpe,
                                    dinv, t, nchunks, N, NR);
    k_agg1<<<(N + 7) / 8, 256, 0, stream>>>(t, dinv, rps, rpe, srt, b1, w2l, q, N);
    k_agg2<<<((size_t)N * 16 + 255) / 256, 256, 0, stream>>>(q, dinv, rps, rpe, srt, p, N);
    k_pool<<<512, 64, 0, stream>>>(p, batch, b2, Wl, bl, (float*)d_out, N, 512);
}